// Round 2
// baseline (208.178 us; speedup 1.0000x reference)
//
#include <hip/hip_runtime.h>
#include <math.h>

// Top-8 (sorted descending) along last axis of (1024, 256, 128) fp32.
// Wave-autonomous: each 64-lane wave owns 64 rows and its own LDS slice
// (no __syncthreads anywhere). Register-prefetch double buffering.
// Insertion into the sorted-8 list uses the med3 identity:
//   s0' = max(s0, v);  s_i' = med3(s_{i-1}, s_i, v)   [8 independent ops]

#define NC      128
#define CHUNK   32
#define NCHUNKS 4
#define WPB     4                  // waves per block
#define TPB     (WPB * 64)         // 256 threads
#define STRIDE  36                 // LDS floats per row: 144 B, 16B-aligned

__device__ __forceinline__ float med3f(float a, float b, float c) {
    return __builtin_amdgcn_fmed3f(a, b, c);
}

#define INS(v) do {                          \
    float n0 = fmaxf(s0, (v));               \
    float n1 = med3f(s0, s1, (v));           \
    float n2 = med3f(s1, s2, (v));           \
    float n3 = med3f(s2, s3, (v));           \
    float n4 = med3f(s3, s4, (v));           \
    float n5 = med3f(s4, s5, (v));           \
    float n6 = med3f(s5, s6, (v));           \
    float n7 = med3f(s6, s7, (v));           \
    s0 = n0; s1 = n1; s2 = n2; s3 = n3;      \
    s4 = n4; s5 = n5; s6 = n6; s7 = n7;      \
} while (0)

__global__ __launch_bounds__(TPB) void topk8_kernel(const float* __restrict__ x,
                                                    float* __restrict__ out) {
    __shared__ float lds[WPB][64 * STRIDE];

    const int w = threadIdx.x >> 6;            // wave id in block
    const int l = threadIdx.x & 63;            // lane id
    const long rowBase = (long)blockIdx.x * TPB + (long)w * 64;
    const float* __restrict__ xw = x + rowBase * NC;
    float* const ldsw = lds[w];

    // Staging map: this lane handles float4 slots f = l + 64k (k=0..7):
    // local row rl = f>>3 in [0,64), col-slot c4 = f&7 in [0,8).
    // Global loads: 8 consecutive lanes cover 128 B contiguous -> coalesced.
    int rl[8], c4[8];
    #pragma unroll
    for (int k = 0; k < 8; ++k) {
        const int f = l + 64 * k;
        rl[k] = f >> 3;
        c4[k] = f & 7;
    }

    // Prologue: load chunk 0 into registers.
    float4 buf[8];
    #pragma unroll
    for (int k = 0; k < 8; ++k)
        buf[k] = *reinterpret_cast<const float4*>(xw + (long)rl[k] * NC + c4[k] * 4);

    float s0 = -INFINITY, s1 = -INFINITY, s2 = -INFINITY, s3 = -INFINITY;
    float s4 = -INFINITY, s5 = -INFINITY, s6 = -INFINITY, s7 = -INFINITY;

    for (int c = 0; c < NCHUNKS; ++c) {
        // Spill registers -> LDS (transpose). Intra-wave ordering via lgkmcnt;
        // no barrier needed: producer and consumer lanes are the same wave.
        #pragma unroll
        for (int k = 0; k < 8; ++k)
            *reinterpret_cast<float4*>(ldsw + rl[k] * STRIDE + c4[k] * 4) = buf[k];

        // Prefetch next chunk while we chew on this one.
        if (c + 1 < NCHUNKS) {
            #pragma unroll
            for (int k = 0; k < 8; ++k)
                buf[k] = *reinterpret_cast<const float4*>(
                    xw + (long)rl[k] * NC + (c + 1) * CHUNK + c4[k] * 4);
        }

        // Consume own row from LDS: 8x ds_read_b128, 32 elements.
        #pragma unroll
        for (int j = 0; j < 8; ++j) {
            const float4 v = *reinterpret_cast<const float4*>(ldsw + l * STRIDE + j * 4);
            INS(v.x); INS(v.y); INS(v.z); INS(v.w);
        }
    }

    // Lane l owns row rowBase+l -> out[(rowBase+l)*8 ..], two float4 stores.
    float* op = out + (rowBase + l) * 8;
    reinterpret_cast<float4*>(op)[0] = make_float4(s0, s1, s2, s3);
    reinterpret_cast<float4*>(op)[1] = make_float4(s4, s5, s6, s7);
}

extern "C" void kernel_launch(void* const* d_in, const int* in_sizes, int n_in,
                              void* d_out, int out_size, void* d_ws, size_t ws_size,
                              hipStream_t stream) {
    const float* x = (const float*)d_in[0];
    float* out     = (float*)d_out;
    const long total = (long)in_sizes[0];   // 1024*256*128
    const int  nrows = (int)(total / NC);   // 262144
    const int  blocks = nrows / TPB;        // 1024, exact
    topk8_kernel<<<blocks, TPB, 0, stream>>>(x, out);
}

// Round 3
// 191.848 us; speedup vs baseline: 1.0851x; 1.0851x over previous
//
#include <hip/hip_runtime.h>
#include <math.h>

// Top-8 (sorted descending) along last axis of (1024, 256, 128) fp32.
// One thread per 128-float row, NO LDS: lane reads its own row with 8x
// global_load_dwordx4 per 32-col chunk (512-B stride across lanes). Every
// 64-B line is fully consumed by the same lane within 4 consecutive loads,
// so HBM traffic is exactly 1x. Register double-buffer hides load latency.
// Sorted-insert via the med3 identity: s0'=max(s0,v); s_i'=med3(s_{i-1},s_i,v)
// -> 8 independent VALU ops per element (no serial chain).

#define NC   128
#define TPB  256

__device__ __forceinline__ float med3f(float a, float b, float c) {
    return __builtin_amdgcn_fmed3f(a, b, c);
}

#define INS(v) do {                          \
    float n0 = fmaxf(s0, (v));               \
    float n1 = med3f(s0, s1, (v));           \
    float n2 = med3f(s1, s2, (v));           \
    float n3 = med3f(s2, s3, (v));           \
    float n4 = med3f(s3, s4, (v));           \
    float n5 = med3f(s4, s5, (v));           \
    float n6 = med3f(s5, s6, (v));           \
    float n7 = med3f(s6, s7, (v));           \
    s0 = n0; s1 = n1; s2 = n2; s3 = n3;      \
    s4 = n4; s5 = n5; s6 = n6; s7 = n7;      \
} while (0)

__global__ __launch_bounds__(TPB) void topk8_kernel(const float* __restrict__ x,
                                                    float* __restrict__ out) {
    const long row = (long)blockIdx.x * TPB + threadIdx.x;
    const float4* __restrict__ xr =
        reinterpret_cast<const float4*>(x + row * NC);   // 32 float4 per row

    float s0 = -INFINITY, s1 = -INFINITY, s2 = -INFINITY, s3 = -INFINITY;
    float s4 = -INFINITY, s5 = -INFINITY, s6 = -INFINITY, s7 = -INFINITY;

    float4 a[8], b[8];

    // Prologue: chunk 0 (cols 0..31) into registers, 8 independent loads.
    #pragma unroll
    for (int j = 0; j < 8; ++j) a[j] = xr[j];

    #pragma unroll
    for (int c = 0; c < 4; ++c) {
        // Prefetch next chunk while chewing on this one.
        if (c < 3) {
            #pragma unroll
            for (int j = 0; j < 8; ++j) b[j] = xr[(c + 1) * 8 + j];
        }
        #pragma unroll
        for (int j = 0; j < 8; ++j) {
            const float4 v = a[j];
            INS(v.x); INS(v.y); INS(v.z); INS(v.w);
        }
        if (c < 3) {
            #pragma unroll
            for (int j = 0; j < 8; ++j) a[j] = b[j];   // renamed away when unrolled
        }
    }

    // Row r writes out[r*8 .. r*8+7]; two float4 stores, jointly coalesced.
    float4* op = reinterpret_cast<float4*>(out + row * 8);
    op[0] = make_float4(s0, s1, s2, s3);
    op[1] = make_float4(s4, s5, s6, s7);
}

extern "C" void kernel_launch(void* const* d_in, const int* in_sizes, int n_in,
                              void* d_out, int out_size, void* d_ws, size_t ws_size,
                              hipStream_t stream) {
    const float* x = (const float*)d_in[0];
    float* out     = (float*)d_out;
    const long total = (long)in_sizes[0];   // 1024*256*128
    const int  nrows = (int)(total / NC);   // 262144
    const int  blocks = nrows / TPB;        // 1024, exact
    topk8_kernel<<<blocks, TPB, 0, stream>>>(x, out);
}

// Round 4
// 186.913 us; speedup vs baseline: 1.1138x; 1.0264x over previous
//
#include <hip/hip_runtime.h>
#include <math.h>

// Top-8 (sorted desc) along last axis of (1024, 256, 128) fp32.
// 8 lanes cooperate per row: perfectly coalesced loads (16 lines/instr),
// per-lane med3 sorted-insert over 16 elements, then 3-stage shuffle
// butterfly using the bitonic-halver identity:
//   top8(A ∪ B) = { max(a_i, b_{7-i}) }  (bitonic) -> 12-CE bitonic sort.
// No LDS, no barriers.

#define NC   128
#define TPB  256

__device__ __forceinline__ float med3f(float a, float b, float c) {
    return __builtin_amdgcn_fmed3f(a, b, c);
}

// compare-exchange, descending: a keeps max, b keeps min
#define CE(a, b) do { float _t = fmaxf(a, b); b = fminf(a, b); a = _t; } while (0)

#define INS(v) do {                          \
    float n0 = fmaxf(s0, (v));               \
    float n1 = med3f(s0, s1, (v));           \
    float n2 = med3f(s1, s2, (v));           \
    float n3 = med3f(s2, s3, (v));           \
    float n4 = med3f(s3, s4, (v));           \
    float n5 = med3f(s4, s5, (v));           \
    float n6 = med3f(s5, s6, (v));           \
    float n7 = med3f(s6, s7, (v));           \
    s0 = n0; s1 = n1; s2 = n2; s3 = n3;      \
    s4 = n4; s5 = n5; s6 = n6; s7 = n7;      \
} while (0)

__global__ __launch_bounds__(TPB) void topk8_kernel(const float* __restrict__ x,
                                                    float* __restrict__ out) {
    const int lane = threadIdx.x & 63;
    const int s    = lane & 7;     // sub-lane within the 8-lane row group
    const int g    = lane >> 3;    // row group within wave (0..7)
    const int w    = threadIdx.x >> 6;                   // wave in block
    const long rowBase = (long)blockIdx.x * 32 + w * 8;  // 8 rows/wave
    const long row     = rowBase + g;
    const float* __restrict__ xr = x + row * NC;

    // 4 loads: float4 slot s+8j. For fixed j, lanes s=0..7 cover 128
    // contiguous bytes of the row -> 16 cache lines per wave instruction.
    const float4 v0 = *reinterpret_cast<const float4*>(xr + (s +  0) * 4);
    const float4 v1 = *reinterpret_cast<const float4*>(xr + (s +  8) * 4);
    const float4 v2 = *reinterpret_cast<const float4*>(xr + (s + 16) * 4);
    const float4 v3 = *reinterpret_cast<const float4*>(xr + (s + 24) * 4);

    float s0 = -INFINITY, s1 = -INFINITY, s2 = -INFINITY, s3 = -INFINITY;
    float s4 = -INFINITY, s5 = -INFINITY, s6 = -INFINITY, s7 = -INFINITY;

    INS(v0.x); INS(v0.y); INS(v0.z); INS(v0.w);
    INS(v1.x); INS(v1.y); INS(v1.z); INS(v1.w);
    INS(v2.x); INS(v2.y); INS(v2.z); INS(v2.w);
    INS(v3.x); INS(v3.y); INS(v3.z); INS(v3.w);

    // Butterfly merge across the 8 lanes of the group (masks 1,2,4 stay
    // inside the group). Both butterfly partners compute the same multiset.
    #pragma unroll
    for (int m = 1; m <= 4; m <<= 1) {
        const float b0 = __shfl_xor(s0, m);
        const float b1 = __shfl_xor(s1, m);
        const float b2 = __shfl_xor(s2, m);
        const float b3 = __shfl_xor(s3, m);
        const float b4 = __shfl_xor(s4, m);
        const float b5 = __shfl_xor(s5, m);
        const float b6 = __shfl_xor(s6, m);
        const float b7 = __shfl_xor(s7, m);
        // halver: top-8 of union (bitonic result)
        float t0 = fmaxf(s0, b7), t1 = fmaxf(s1, b6);
        float t2 = fmaxf(s2, b5), t3 = fmaxf(s3, b4);
        float t4 = fmaxf(s4, b3), t5 = fmaxf(s5, b2);
        float t6 = fmaxf(s6, b1), t7 = fmaxf(s7, b0);
        // bitonic merge network, descending
        CE(t0, t4); CE(t1, t5); CE(t2, t6); CE(t3, t7);
        CE(t0, t2); CE(t1, t3); CE(t4, t6); CE(t5, t7);
        CE(t0, t1); CE(t2, t3); CE(t4, t5); CE(t6, t7);
        s0 = t0; s1 = t1; s2 = t2; s3 = t3;
        s4 = t4; s5 = t5; s6 = t6; s7 = t7;
    }

    // All 8 lanes of a group hold the identical sorted list; lane s stores
    // element s. Flat address = rowBase*8 + lane -> 256 B contiguous/wave.
    const float r = s == 0 ? s0 : s == 1 ? s1 : s == 2 ? s2 : s == 3 ? s3
                  : s == 4 ? s4 : s == 5 ? s5 : s == 6 ? s6 : s7;
    out[row * 8 + s] = r;
}

extern "C" void kernel_launch(void* const* d_in, const int* in_sizes, int n_in,
                              void* d_out, int out_size, void* d_ws, size_t ws_size,
                              hipStream_t stream) {
    const float* x = (const float*)d_in[0];
    float* out     = (float*)d_out;
    const long total = (long)in_sizes[0];   // 1024*256*128
    const int  nrows = (int)(total / NC);   // 262144
    const int  blocks = nrows / 32;         // 32 rows per 256-thread block
    topk8_kernel<<<blocks, TPB, 0, stream>>>(x, out);
}

// Round 5
// 186.648 us; speedup vs baseline: 1.1154x; 1.0014x over previous
//
#include <hip/hip_runtime.h>
#include <math.h>

// Top-8 (sorted desc) along last axis of (1024, 256, 128) fp32.
// 4 lanes cooperate per row. Each lane: 8x global_load_dwordx4 issued
// up-front (128 B in flight), med3 sorted-insert of its 32 elements,
// then 2 shuffle-butterfly merge stages (masks 1,2) using the bitonic
// halver  top8(A ∪ B) = { max(a_i, b_{7-i}) }  + 12-CE bitonic merge.
// Store: lane s writes float2 {e[2s], e[2s+1]} -> contiguous.
// No LDS, no barriers.

#define NC   128
#define TPB  256

__device__ __forceinline__ float med3f(float a, float b, float c) {
    return __builtin_amdgcn_fmed3f(a, b, c);
}

// compare-exchange, descending: a keeps max, b keeps min
#define CE(a, b) do { float _t = fmaxf(a, b); b = fminf(a, b); a = _t; } while (0)

#define INS(v) do {                          \
    float n0 = fmaxf(s0, (v));               \
    float n1 = med3f(s0, s1, (v));           \
    float n2 = med3f(s1, s2, (v));           \
    float n3 = med3f(s2, s3, (v));           \
    float n4 = med3f(s3, s4, (v));           \
    float n5 = med3f(s4, s5, (v));           \
    float n6 = med3f(s5, s6, (v));           \
    float n7 = med3f(s6, s7, (v));           \
    s0 = n0; s1 = n1; s2 = n2; s3 = n3;      \
    s4 = n4; s5 = n5; s6 = n6; s7 = n7;      \
} while (0)

__global__ __launch_bounds__(TPB) void topk8_kernel(const float* __restrict__ x,
                                                    float* __restrict__ out) {
    const int lane = threadIdx.x & 63;
    const int s    = lane & 3;     // sub-lane within the 4-lane row group
    const int g    = lane >> 2;    // row group within wave (0..15)
    const int w    = threadIdx.x >> 6;                    // wave in block
    const long rowBase = (long)blockIdx.x * 64 + w * 16;  // 16 rows/wave
    const long row     = rowBase + g;
    const float* __restrict__ xr = x + row * NC;

    // 8 loads, float4 slot s+4j: per instruction the wave covers one 64-B
    // line per row x 16 rows; across j=0..7 a contiguous 8-KiB span.
    float4 v[8];
    #pragma unroll
    for (int j = 0; j < 8; ++j)
        v[j] = *reinterpret_cast<const float4*>(xr + (s + 4 * j) * 4);

    float s0 = -INFINITY, s1 = -INFINITY, s2 = -INFINITY, s3 = -INFINITY;
    float s4 = -INFINITY, s5 = -INFINITY, s6 = -INFINITY, s7 = -INFINITY;

    #pragma unroll
    for (int j = 0; j < 8; ++j) {
        INS(v[j].x); INS(v[j].y); INS(v[j].z); INS(v[j].w);
    }

    // 2 butterfly stages (masks 1,2 stay inside the 4-lane group).
    #pragma unroll
    for (int m = 1; m <= 2; m <<= 1) {
        const float b0 = __shfl_xor(s0, m);
        const float b1 = __shfl_xor(s1, m);
        const float b2 = __shfl_xor(s2, m);
        const float b3 = __shfl_xor(s3, m);
        const float b4 = __shfl_xor(s4, m);
        const float b5 = __shfl_xor(s5, m);
        const float b6 = __shfl_xor(s6, m);
        const float b7 = __shfl_xor(s7, m);
        // halver: top-8 of union (result bitonic)
        float t0 = fmaxf(s0, b7), t1 = fmaxf(s1, b6);
        float t2 = fmaxf(s2, b5), t3 = fmaxf(s3, b4);
        float t4 = fmaxf(s4, b3), t5 = fmaxf(s5, b2);
        float t6 = fmaxf(s6, b1), t7 = fmaxf(s7, b0);
        // bitonic merge network, descending
        CE(t0, t4); CE(t1, t5); CE(t2, t6); CE(t3, t7);
        CE(t0, t2); CE(t1, t3); CE(t4, t6); CE(t5, t7);
        CE(t0, t1); CE(t2, t3); CE(t4, t5); CE(t6, t7);
        s0 = t0; s1 = t1; s2 = t2; s3 = t3;
        s4 = t4; s5 = t5; s6 = t6; s7 = t7;
    }

    // All 4 lanes hold the full sorted list; lane s stores elements
    // {2s, 2s+1} as one float2 -> 32 B contiguous per row, 512 B per wave.
    const float r0 = s == 0 ? s0 : s == 1 ? s2 : s == 2 ? s4 : s6;
    const float r1 = s == 0 ? s1 : s == 1 ? s3 : s == 2 ? s5 : s7;
    *reinterpret_cast<float2*>(out + row * 8 + s * 2) = make_float2(r0, r1);
}

extern "C" void kernel_launch(void* const* d_in, const int* in_sizes, int n_in,
                              void* d_out, int out_size, void* d_ws, size_t ws_size,
                              hipStream_t stream) {
    const float* x = (const float*)d_in[0];
    float* out     = (float*)d_out;
    const long total = (long)in_sizes[0];   // 1024*256*128
    const int  nrows = (int)(total / NC);   // 262144
    const int  blocks = nrows / 64;         // 64 rows per 256-thread block
    topk8_kernel<<<blocks, TPB, 0, stream>>>(x, out);
}